// Round 1
// baseline (1696.162 us; speedup 1.0000x reference)
//
#include <hip/hip_runtime.h>

#define N_NODES 50000
#define N_EDGES 800000
#define BATCH   4
#define DIM     64
#define NEG_SLOPE 0.2f

// ---------------------------------------------------------------------------
// Index dtype detector: reference uses int64, harness doc says int32.
// If int64 (little-endian, values < 2^31), every odd int32 word is 0.
// If int32, 64 random values in [0,50000) are ~never all zero.
// Writes flag=1 for int64, 0 for int32. Deterministic given inputs.
// ---------------------------------------------------------------------------
__global__ void detect_idx_kernel(const unsigned* __restrict__ ei, int* flag) {
    __shared__ int any;
    if (threadIdx.x == 0) any = 0;
    __syncthreads();
    unsigned v = ei[threadIdx.x * 2 + 1];
    if (v != 0) atomicOr(&any, 1);
    __syncthreads();
    if (threadIdx.x == 0) *flag = (any ? 0 : 1);
}

__device__ __forceinline__ int load_idx(const void* p, long long i, int is64) {
    if (is64) return (int)(((const long long*)p)[i]);
    return ((const int*)p)[i];
}

// ---------------------------------------------------------------------------
// dst[r][d] = bias[d] for r in [0, rows)
// ---------------------------------------------------------------------------
__global__ __launch_bounds__(256)
void fill_bias_kernel(float* __restrict__ dst, const float* __restrict__ bias,
                      long long total) {
    long long i = (long long)blockIdx.x * blockDim.x + threadIdx.x;
    long long stride = (long long)gridDim.x * blockDim.x;
    for (; i < total; i += stride) dst[i] = bias[i & (DIM - 1)];
}

// ---------------------------------------------------------------------------
// S = act(X) @ W   for one [N_NODES, 64] x [64, 64] slab.
// Block = 256 threads = 4 waves; wave handles one row at a time (lane = col d).
// Each block: 16 rows. W staged in LDS (16 KB); x row elements broadcast-read.
// ---------------------------------------------------------------------------
template <bool LEAKY>
__global__ __launch_bounds__(256)
void gemm_kernel(const float* __restrict__ X, const float* __restrict__ W,
                 float* __restrict__ S) {
    __shared__ float Wl[64][64];
    int t = threadIdx.x;
    for (int i = t; i < 64 * 64; i += 256) Wl[i >> 6][i & 63] = W[i];
    __syncthreads();

    int d  = t & 63;
    int ry = t >> 6;                 // 0..3
    int rowBase = blockIdx.x * 16;
    for (int r = ry; r < 16; r += 4) {
        int row = rowBase + r;
        if (row >= N_NODES) continue;
        const float* xr = X + (long long)row * DIM;
        float acc = 0.f;
#pragma unroll
        for (int k = 0; k < 64; k += 4) {
            float4 xv = *(const float4*)(xr + k);
            if (LEAKY) {
                xv.x = xv.x > 0.f ? xv.x : NEG_SLOPE * xv.x;
                xv.y = xv.y > 0.f ? xv.y : NEG_SLOPE * xv.y;
                xv.z = xv.z > 0.f ? xv.z : NEG_SLOPE * xv.z;
                xv.w = xv.w > 0.f ? xv.w : NEG_SLOPE * xv.w;
            }
            acc += xv.x * Wl[k + 0][d];
            acc += xv.y * Wl[k + 1][d];
            acc += xv.z * Wl[k + 2][d];
            acc += xv.w * Wl[k + 3][d];
        }
        S[(long long)row * DIM + d] = acc;
    }
}

// ---------------------------------------------------------------------------
// Scatter-aggregate: for each edge e of graphs [bStart, bStart+nGraphs):
//   dst[g*dstStride + row*64 + lane] += ew * src[col*64 + lane]
// One wave per edge per iteration; lane = feature.
// src is graph-independent (support0 shared, or per-graph pre-offset).
// ---------------------------------------------------------------------------
__global__ __launch_bounds__(256)
void scatter_kernel(const void* __restrict__ ei, const float* __restrict__ ew,
                    const float* __restrict__ src, float* dst,
                    const int* __restrict__ flag, int nGraphs, int bStart,
                    long long dstStride) {
    const int is64 = *flag;
    const int lane = threadIdx.x & 63;
    const int wpb  = blockDim.x >> 6;
    long long wid  = (long long)blockIdx.x * wpb + (threadIdx.x >> 6);
    const long long nw    = (long long)gridDim.x * wpb;
    const long long total = (long long)nGraphs * N_EDGES;
    for (long long e = wid; e < total; e += nw) {
        int g = (int)(e / N_EDGES);
        long long eb = e - (long long)g * N_EDGES;
        int b = g + bStart;
        long long ib = (long long)b * (2LL * N_EDGES);
        int row = load_idx(ei, ib + eb, is64);
        int col = load_idx(ei, ib + N_EDGES + eb, is64);
        float w = ew[(long long)b * N_EDGES + eb];
        float v = w * src[(long long)col * DIM + lane];
        atomicAdd(dst + g * dstStride + (long long)row * DIM + lane, v);
    }
}

extern "C" void kernel_launch(void* const* d_in, const int* in_sizes, int n_in,
                              void* d_out, int out_size, void* d_ws, size_t ws_size,
                              hipStream_t stream) {
    const float* bx = (const float*)d_in[0];
    const void*  ei = d_in[1];
    const float* ew = (const float*)d_in[2];
    const float* W0 = (const float*)d_in[3];
    const float* b0 = (const float*)d_in[4];
    const float* W1 = (const float*)d_in[5];
    const float* b1 = (const float*)d_in[6];
    float* out = (float*)d_out;

    char* ws = (char*)d_ws;
    int*   flag     = (int*)ws;
    float* support0 = (float*)(ws + 256);
    float* support1 = support0 + (long long)N_NODES * DIM;
    const long long ND = (long long)N_NODES * DIM;

    // 1) index dtype detect
    detect_idx_kernel<<<1, 64, 0, stream>>>((const unsigned*)ei, flag);

    // 2) h1 pre-accumulator (stored in d_out): init all graphs to b0
    fill_bias_kernel<<<2048, 256, 0, stream>>>(out, b0, (long long)BATCH * ND);

    // 3) support0 = bx @ W0  (graph-independent, computed once)
    gemm_kernel<false><<<(N_NODES + 15) / 16, 256, 0, stream>>>(bx, W0, support0);

    // 4) layer-1 scatter for all 4 graphs into d_out (pre-activation h1)
    scatter_kernel<<<4096, 256, 0, stream>>>(ei, ew, support0, out, flag,
                                             BATCH, 0, ND);

    // 5) per graph: support1 = leaky_relu(h1) @ W1 ; out = b1 + scatter(support1)
    for (int b = 0; b < BATCH; ++b) {
        float* outb = out + (long long)b * ND;
        gemm_kernel<true><<<(N_NODES + 15) / 16, 256, 0, stream>>>(outb, W1, support1);
        fill_bias_kernel<<<1024, 256, 0, stream>>>(outb, b1, ND);
        scatter_kernel<<<2048, 256, 0, stream>>>(ei, ew, support1, outb, flag,
                                                 1, b, 0);
    }
}

// Round 2
// 1181.368 us; speedup vs baseline: 1.4358x; 1.4358x over previous
//
#include <hip/hip_runtime.h>

#define N_NODES 50000
#define N_EDGES 800000
#define BATCH   4
#define DIM     64
#define NEG_SLOPE 0.2f

// ---------------------------------------------------------------------------
// Index dtype detector (int64 vs int32): if int64 little-endian with values
// < 2^31, every odd 32-bit word is 0. Writes flag=1 for int64, 0 for int32.
// ---------------------------------------------------------------------------
__global__ void detect_idx_kernel(const unsigned* __restrict__ ei, int* flag) {
    __shared__ int any;
    if (threadIdx.x == 0) any = 0;
    __syncthreads();
    unsigned v = ei[threadIdx.x * 2 + 1];
    if (v != 0) atomicOr(&any, 1);
    __syncthreads();
    if (threadIdx.x == 0) *flag = (any ? 0 : 1);
}

__device__ __forceinline__ int load_idx(const void* p, long long i, int is64) {
    if (is64) return (int)(((const long long*)p)[i]);
    return ((const int*)p)[i];
}

// ---------------------------------------------------------------------------
// CSR build step 1: deg[row]++ over one graph's edges.
// ---------------------------------------------------------------------------
__global__ __launch_bounds__(256)
void histogram_kernel(const void* __restrict__ ei, const int* __restrict__ flag,
                      int b, int* __restrict__ deg) {
    const int is64 = *flag;
    const long long base = (long long)b * (2LL * N_EDGES);
    long long i = (long long)blockIdx.x * blockDim.x + threadIdx.x;
    long long stride = (long long)gridDim.x * blockDim.x;
    for (; i < N_EDGES; i += stride) {
        int row = load_idx(ei, base + i, is64);
        atomicAdd(&deg[row], 1);
    }
}

// ---------------------------------------------------------------------------
// CSR build step 2: exclusive scan of deg -> rowptr (N+1) and cursor copy.
// Single block of 1024 threads, Hillis-Steele per 1024-chunk + running offset.
// ---------------------------------------------------------------------------
__global__ __launch_bounds__(1024)
void scan_kernel(const int* __restrict__ deg, int* __restrict__ rowptr,
                 int* __restrict__ cursor) {
    __shared__ int sdata[1024];
    __shared__ int run;
    int t = threadIdx.x;
    if (t == 0) run = 0;
    __syncthreads();
    for (int base = 0; base < N_NODES; base += 1024) {
        int idx = base + t;
        int v = (idx < N_NODES) ? deg[idx] : 0;
        sdata[t] = v;
        __syncthreads();
        for (int off = 1; off < 1024; off <<= 1) {
            int x = (t >= off) ? sdata[t - off] : 0;
            __syncthreads();
            sdata[t] += x;
            __syncthreads();
        }
        int excl = sdata[t] - v;
        if (idx < N_NODES) {
            int p = run + excl;
            rowptr[idx] = p;
            cursor[idx] = p;
        }
        __syncthreads();
        if (t == 1023) run += sdata[1023];
        __syncthreads();
    }
    if (t == 0) rowptr[N_NODES] = run;
}

// ---------------------------------------------------------------------------
// CSR build step 3: place (col, weight) pairs sorted by row via cursor.
// ---------------------------------------------------------------------------
__global__ __launch_bounds__(256)
void placement_kernel(const void* __restrict__ ei, const float* __restrict__ ew,
                      const int* __restrict__ flag, int b,
                      int* __restrict__ cursor, int2* __restrict__ colw) {
    const int is64 = *flag;
    const long long base = (long long)b * (2LL * N_EDGES);
    const float* ewb = ew + (long long)b * N_EDGES;
    long long i = (long long)blockIdx.x * blockDim.x + threadIdx.x;
    long long stride = (long long)gridDim.x * blockDim.x;
    for (; i < N_EDGES; i += stride) {
        int row = load_idx(ei, base + i, is64);
        int col = load_idx(ei, base + N_EDGES + i, is64);
        int pos = atomicAdd(&cursor[row], 1);
        colw[pos] = make_int2(col, __float_as_int(ewb[i]));
    }
}

// ---------------------------------------------------------------------------
// S = act(X) @ W. W staged in LDS; each thread computes 4 consecutive output
// cols for a row (ds_read_b128 for W, float4 store). Block = 256 thr, 64 rows.
// ---------------------------------------------------------------------------
template <bool LEAKY>
__global__ __launch_bounds__(256)
void gemm_kernel(const float* __restrict__ X, const float* __restrict__ W,
                 float* __restrict__ S) {
    __shared__ float Wl[64 * 64];
    int t = threadIdx.x;
    for (int i = t; i < 64 * 64; i += 256) Wl[i] = W[i];
    __syncthreads();

    int dq = t & 15;       // output col quad: cols 4*dq .. 4*dq+3
    int rl = t >> 4;       // local row 0..15
    int rowBase = blockIdx.x * 64;
    for (int r = rl; r < 64; r += 16) {
        int row = rowBase + r;
        if (row >= N_NODES) break;
        const float* xr = X + (long long)row * DIM;
        float4 acc = {0.f, 0.f, 0.f, 0.f};
#pragma unroll
        for (int k = 0; k < 64; k += 4) {
            float4 xv = *(const float4*)(xr + k);
            if (LEAKY) {
                xv.x = xv.x > 0.f ? xv.x : NEG_SLOPE * xv.x;
                xv.y = xv.y > 0.f ? xv.y : NEG_SLOPE * xv.y;
                xv.z = xv.z > 0.f ? xv.z : NEG_SLOPE * xv.z;
                xv.w = xv.w > 0.f ? xv.w : NEG_SLOPE * xv.w;
            }
#pragma unroll
            for (int kk = 0; kk < 4; ++kk) {
                float xs = kk == 0 ? xv.x : kk == 1 ? xv.y : kk == 2 ? xv.z : xv.w;
                float4 wv = *(const float4*)(&Wl[(k + kk) * 64 + dq * 4]);
                acc.x += xs * wv.x;
                acc.y += xs * wv.y;
                acc.z += xs * wv.z;
                acc.w += xs * wv.w;
            }
        }
        *(float4*)(S + (long long)row * DIM + dq * 4) = acc;
    }
}

// ---------------------------------------------------------------------------
// Pull aggregation: one wave per node, lane = feature.
// dst[node][lane] = bias[lane] + sum_e w_e * src[col_e][lane]
// ---------------------------------------------------------------------------
__global__ __launch_bounds__(256)
void aggregate_kernel(const int* __restrict__ rowptr, const int2* __restrict__ colw,
                      const float* __restrict__ src, const float* __restrict__ bias,
                      float* __restrict__ dst) {
    int lane = threadIdx.x & 63;
    int node = blockIdx.x * 4 + (threadIdx.x >> 6);
    if (node >= N_NODES) return;
    int s = rowptr[node];
    int e = rowptr[node + 1];
    float acc = bias[lane];
    int k = s;
    for (; k + 4 <= e; k += 4) {
        int2 c0 = colw[k + 0];
        int2 c1 = colw[k + 1];
        int2 c2 = colw[k + 2];
        int2 c3 = colw[k + 3];
        float v0 = src[(long long)c0.x * DIM + lane];
        float v1 = src[(long long)c1.x * DIM + lane];
        float v2 = src[(long long)c2.x * DIM + lane];
        float v3 = src[(long long)c3.x * DIM + lane];
        acc += __int_as_float(c0.y) * v0;
        acc += __int_as_float(c1.y) * v1;
        acc += __int_as_float(c2.y) * v2;
        acc += __int_as_float(c3.y) * v3;
    }
    for (; k < e; ++k) {
        int2 c = colw[k];
        acc += __int_as_float(c.y) * src[(long long)c.x * DIM + lane];
    }
    dst[(long long)node * DIM + lane] = acc;
}

extern "C" void kernel_launch(void* const* d_in, const int* in_sizes, int n_in,
                              void* d_out, int out_size, void* d_ws, size_t ws_size,
                              hipStream_t stream) {
    const float* bx = (const float*)d_in[0];
    const void*  ei = d_in[1];
    const float* ew = (const float*)d_in[2];
    const float* W0 = (const float*)d_in[3];
    const float* b0 = (const float*)d_in[4];
    const float* W1 = (const float*)d_in[5];
    const float* b1 = (const float*)d_in[6];
    float* out = (float*)d_out;

    // workspace layout (~19.8 MB)
    char* ws = (char*)d_ws;
    int*   flag    = (int*)ws;                          // 256 B slot
    int*   deg     = (int*)(ws + 256);                  // 50000 ints
    int*   cursor  = deg + 50048;                       // 50000 ints
    int*   rowptr  = cursor + 50048;                    // 50001 ints
    int2*  colw    = (int2*)(ws + 256 + 3 * 50048 * 4 + 64);  // 800000 int2
    float* support = (float*)((char*)colw + (long long)N_EDGES * 8 + 64);
    const long long ND = (long long)N_NODES * DIM;

    detect_idx_kernel<<<1, 64, 0, stream>>>((const unsigned*)ei, flag);

    for (int b = 0; b < BATCH; ++b) {
        float* outb = out + (long long)b * ND;

        // --- build CSR for graph b (shared by both layers) ---
        hipMemsetAsync(deg, 0, N_NODES * sizeof(int), stream);
        histogram_kernel<<<1024, 256, 0, stream>>>(ei, flag, b, deg);
        scan_kernel<<<1, 1024, 0, stream>>>(deg, rowptr, cursor);
        placement_kernel<<<1024, 256, 0, stream>>>(ei, ew, flag, b, cursor, colw);

        // --- layer 1: support = bx @ W0 ; h1 = agg + b0 (pre-activation) ---
        gemm_kernel<false><<<(N_NODES + 63) / 64, 256, 0, stream>>>(bx, W0, support);
        aggregate_kernel<<<(N_NODES + 3) / 4, 256, 0, stream>>>(rowptr, colw, support,
                                                                b0, outb);

        // --- layer 2: support = leaky(h1) @ W1 ; out = agg + b1 ---
        gemm_kernel<true><<<(N_NODES + 63) / 64, 256, 0, stream>>>(outb, W1, support);
        aggregate_kernel<<<(N_NODES + 3) / 4, 256, 0, stream>>>(rowptr, colw, support,
                                                                b1, outb);
    }
}